// Round 12
// baseline (266.524 us; speedup 1.0000x reference)
//
#include <hip/hip_runtime.h>
#include <hip/hip_bf16.h>
#include <stdint.h>

typedef unsigned short u16;
typedef __attribute__((ext_vector_type(8))) __bf16 bf16x8;
typedef __attribute__((ext_vector_type(4))) float f32x4;

#define QS 3072   // row stride of fused qkv buffer

#define DEV static __device__ __forceinline__

DEV u16 f2bf(float f){
  __hip_bfloat16 h = __float2bfloat16(f);
  return *reinterpret_cast<u16*>(&h);
}
DEV float bf2f(u16 u){
  __hip_bfloat16 h;
  *reinterpret_cast<u16*>(&h) = u;
  return __bfloat162float(h);
}
DEV f32x4 mfma16(bf16x8 a, bf16x8 b, f32x4 c){
  return __builtin_amdgcn_mfma_f32_16x16x32_bf16(a, b, c, 0, 0, 0);
}
DEV bf16x8 ldfrag(const u16* p){ return *reinterpret_cast<const bf16x8*>(p); }
DEV u16 u4get(ushort4 v, int d){ return d==0?v.x: d==1?v.y: d==2?v.z: v.w; }
DEV float f4get(float4 v, int d){ return d==0?v.x: d==1?v.y: d==2?v.z: v.w; }

DEV void gl_lds16(const u16* g, u16* l){
  __builtin_amdgcn_global_load_lds(
      (const __attribute__((address_space(1))) void*)g,
      (__attribute__((address_space(3))) void*)l, 16, 0, 0);
}

// counted-vmcnt + barrier (T4): keep later stage loads in flight across barrier
template<int N> DEV void wait_vmb(){
  if constexpr (N == 0)      asm volatile("s_waitcnt vmcnt(0)\ns_barrier" ::: "memory");
  else if constexpr (N == 2) asm volatile("s_waitcnt vmcnt(2)\ns_barrier" ::: "memory");
  else if constexpr (N == 3) asm volatile("s_waitcnt vmcnt(3)\ns_barrier" ::: "memory");
  else                       asm volatile("s_waitcnt vmcnt(4)\ns_barrier" ::: "memory");
}

// ---------------------------------------------------------------- prep
__global__ void k_prep(const float* __restrict__ x, u16* __restrict__ xb,
                       const float* __restrict__ s0, const float* __restrict__ s1,
                       const float* __restrict__ s2, const float* __restrict__ s3,
                       const float* __restrict__ s4,
                       u16* __restrict__ d0, u16* __restrict__ d1,
                       u16* __restrict__ d2, u16* __restrict__ d3,
                       u16* __restrict__ d4){
  const int z = blockIdx.z;
  if (z >= 5){
    int lb  = (z - 5) * 1024 + blockIdx.y * 32 + blockIdx.x;
    int tid = threadIdx.y * 32 + threadIdx.x;
    size_t i = ((size_t)lb * 256 + tid) * 4;
    float4 v = *reinterpret_cast<const float4*>(x + i);
    ushort4 o;
    o.x = f2bf(v.x); o.y = f2bf(v.y); o.z = f2bf(v.z); o.w = f2bf(v.w);
    *reinterpret_cast<ushort4*>(xb + i) = o;
    return;
  }
  const float* src = (z==0)?s0:(z==1)?s1:(z==2)?s2:(z==3)?s3:s4;
  u16* dst = (z==0)?d0:(z==1)?d1:(z==2)?d2:(z==3)?d3:d4;
  const int C = (z==4) ? 256 : 1024;
  int bx = blockIdx.x * 32, by = blockIdx.y * 32;
  if (bx >= C) return;
  __shared__ u16 t[32][33];
  int tx = threadIdx.x;
  for (int dy = threadIdx.y; dy < 32; dy += 8)
    t[dy][tx] = f2bf(src[(size_t)(by + dy) * C + bx + tx]);
  __syncthreads();
  for (int dy = threadIdx.y; dy < 32; dy += 8)
    dst[(size_t)(bx + dy) * 1024 + by + tx] = t[tx][dy];
}

// ---------------------------------------------------------------- 256^2 GEMM
// 256x256 tile, BK=64, 8 waves, 2-buffer LDS, phase-interleaved with COUNTED
// vmcnt (never 0 except last tile) + st_16x32 swizzle + setprio (T2+T3+T4+T5).
// Stage units: 64 rows each; order B0,B1 | B2,B3 | A0,A2 | A1,A3 per tile.
// S1 (vmcnt 2): B* + A-units{0,2} resident (quads 0-1).
// S2 (vmcnt 4): A-units{1,3} resident (quads 2-3); next tile's B stays in flight.
// EPI: 3=fp32 store, 4=qkv (bcol<2048 swish, else copy; bf16 single dest)
template<int EPI>
__global__ __launch_bounds__(512, 2) void k_gemm256(
    const u16* __restrict__ A, const u16* __restrict__ BT,
    int N, void* __restrict__ out0)
{
  __shared__ u16 As[2][256 * 64];
  __shared__ u16 Bs[2][256 * 64];
  const int tid  = threadIdx.x;
  const int lane = tid & 63;
  const int w    = tid >> 6;        // wave 0..7
  const int wm   = w >> 2;          // 0..1 (row half)
  const int wn   = w & 3;           // 0..3 (col quarter)
  const int l15  = lane & 15;
  const int koff = (lane >> 4) * 8;
  const int ksw  = koff ^ (((l15 >> 2) & 1) << 4);   // swizzled read col
  const int srow = w * 8 + (lane >> 3);              // stage row within unit
  const int scol = ((lane & 7) * 8) ^ (((lane >> 5) & 1) << 4); // pre-swz src col
  const int gx = gridDim.x;
  const int npx = gx >> 3;
  const int lin = blockIdx.y * gx + blockIdx.x;
  const int xcd = lin & 7, idx = lin >> 3;
  const int brow = (xcd * npx + (idx % npx)) * 256;
  const int bcol = (idx / npx) * 256;
  constexpr int K = 1024, NT = 16;

  f32x4 acc[8][4];
#pragma unroll
  for (int i = 0; i < 8; i++)
#pragma unroll
    for (int j = 0; j < 4; j++) acc[i][j] = f32x4{0.f, 0.f, 0.f, 0.f};

  auto stA = [&](int buf, int u, int t){
    gl_lds16(A + (size_t)(brow + u * 64 + srow) * K + t * 64 + scol,
             &As[buf][(u * 64 + w * 8) * 64]);
  };
  auto stB = [&](int buf, int u, int t){
    gl_lds16(BT + (size_t)(bcol + u * 64 + srow) * K + t * 64 + scol,
             &Bs[buf][(u * 64 + w * 8) * 64]);
  };

  bf16x8 bf[4][2];
  auto quad = [&](int cur, int p){
    bf16x8 af[2][2];
#pragma unroll
    for (int i = 0; i < 2; i++)
#pragma unroll
      for (int ks = 0; ks < 2; ks++)
        af[i][ks] = ldfrag(&As[cur][(wm * 128 + p * 32 + i * 16 + l15) * 64 + ks * 32 + ksw]);
    __builtin_amdgcn_s_setprio(1);
#pragma unroll
    for (int i = 0; i < 2; i++)
#pragma unroll
      for (int j = 0; j < 4; j++){
        acc[p * 2 + i][j] = mfma16(af[i][0], bf[j][0], acc[p * 2 + i][j]);
        acc[p * 2 + i][j] = mfma16(af[i][1], bf[j][1], acc[p * 2 + i][j]);
      }
    __builtin_amdgcn_s_setprio(0);
  };

  // prologue: tile 0, issue order matches in-loop order
  stB(0, 0, 0); stB(0, 1, 0); stB(0, 2, 0); stB(0, 3, 0);
  stA(0, 0, 0); stA(0, 2, 0); stA(0, 1, 0); stA(0, 3, 0);

  for (int t = 0; t < NT; ++t){
    const int cur = t & 1, nxt = cur ^ 1;
    const bool more = (t + 1 < NT);
    wait_vmb<2>();                    // S1: B*,A0,A2 of tile t resident
    // phase 0: B-frags + quad0 ; stage B0,B1(t+1)
    if (more){ stB(nxt, 0, t + 1); stB(nxt, 1, t + 1); }
#pragma unroll
    for (int j = 0; j < 4; j++)
#pragma unroll
      for (int ks = 0; ks < 2; ks++)
        bf[j][ks] = ldfrag(&Bs[cur][(wn * 64 + j * 16 + l15) * 64 + ks * 32 + ksw]);
    quad(cur, 0);
    // phase 1: quad1 ; stage B2,B3(t+1)
    if (more){ stB(nxt, 2, t + 1); stB(nxt, 3, t + 1); }
    quad(cur, 1);
    // S2: A1,A3 of tile t resident (t+1's B loads stay in flight)
    if (more) wait_vmb<4>(); else wait_vmb<0>();
    // phase 2: quad2 ; stage A0,A2(t+1)
    if (more){ stA(nxt, 0, t + 1); stA(nxt, 2, t + 1); }
    quad(cur, 2);
    // phase 3: quad3 ; stage A1,A3(t+1)
    if (more){ stA(nxt, 1, t + 1); stA(nxt, 3, t + 1); }
    quad(cur, 3);
  }

#pragma unroll
  for (int fi = 0; fi < 8; fi++){
#pragma unroll
    for (int j = 0; j < 4; j++){
#pragma unroll
      for (int r = 0; r < 4; r++){
        int orow = brow + wm * 128 + fi * 16 + (lane >> 4) * 4 + r;
        int ocol = bcol + wn * 64 + j * 16 + l15;
        float v = acc[fi][j][r];
        if constexpr (EPI == 3){
          ((float*)out0)[(size_t)orow * N + ocol] = v;
        } else {
          float o = (bcol < 2048) ? v / (1.f + __expf(-v)) : v;
          ((u16*)out0)[(size_t)orow * N + ocol] = f2bf(o);
        }
      }
    }
  }
}

// ---------------------------------------------------------------- 128^2 GEMM (gate)
template<int EPI, int BM>
__global__ __launch_bounds__(256) void k_gemm(
    const u16* __restrict__ A, const u16* __restrict__ BT,
    int K, int N, void* __restrict__ out0)
{
  __shared__ u16 As[3][BM * 32];
  __shared__ u16 Bs[3][128 * 32];
  const int tid  = threadIdx.x;
  const int lane = tid & 63;
  const int wv   = tid >> 6;
  const int gx  = gridDim.x;
  const int npx = gx >> 3;
  const int lin = blockIdx.y * gx + blockIdx.x;
  const int xcd = lin & 7;
  const int idx = lin >> 3;
  const int brow = (xcd * npx + (idx % npx)) * BM;
  const int bcol = (idx / npx) * 128;
  const int wr   = (wv >> 1) * (BM / 2);
  const int wc   = (wv & 1) * 64;
  const int l15  = lane & 15;
  const int koff = (lane >> 4) * 8;
  const int lr   = lane >> 2;
  const int lc8  = (lane & 3) * 8;
  const int lc8s = lc8 ^ (((lr >> 3) & 1) << 4);
  const int ksw  = koff ^ (((l15 >> 3) & 1) << 4);
  constexpr int MI = BM / 32;
  constexpr int LPS = (BM == 128) ? 4 : 3;

  f32x4 acc[MI][4];
#pragma unroll
  for (int i = 0; i < MI; i++)
#pragma unroll
    for (int j = 0; j < 4; j++) acc[i][j] = f32x4{0.f, 0.f, 0.f, 0.f};

  auto stage = [&](int buf, int kt){
    if constexpr (BM == 128){
#pragma unroll
      for (int j = 0; j < 2; j++){
        int rb = wv * 32 + j * 16;
        gl_lds16(A  + (size_t)(brow + rb + lr) * K + kt + lc8s, &As[buf][rb * 32]);
        gl_lds16(BT + (size_t)(bcol + rb + lr) * K + kt + lc8s, &Bs[buf][rb * 32]);
      }
    } else {
      gl_lds16(A + (size_t)(brow + wv * 16 + lr) * K + kt + lc8s, &As[buf][wv * 16 * 32]);
#pragma unroll
      for (int j = 0; j < 2; j++){
        int rb = wv * 32 + j * 16;
        gl_lds16(BT + (size_t)(bcol + rb + lr) * K + kt + lc8s, &Bs[buf][rb * 32]);
      }
    }
  };

  const int nit = K >> 5;
  stage(0, 0);
  stage(1, 32);
  for (int it = 0; it < nit; it++){
    const int cur = it % 3;
    if (it + 1 < nit) wait_vmb<LPS>();
    else              wait_vmb<0>();
    bf16x8 af[MI], bfv[4];
#pragma unroll
    for (int i = 0; i < MI; i++) af[i]  = ldfrag(&As[cur][(wr + i * 16 + l15) * 32 + ksw]);
#pragma unroll
    for (int j = 0; j < 4; j++) bfv[j] = ldfrag(&Bs[cur][(wc + j * 16 + l15) * 32 + ksw]);
#pragma unroll
    for (int i = 0; i < MI; i++)
#pragma unroll
      for (int j = 0; j < 4; j++)
        acc[i][j] = mfma16(af[i], bfv[j], acc[i][j]);
    if (it + 2 < nit) stage((it + 2) % 3, (it + 2) << 5);
  }

#pragma unroll
  for (int i = 0; i < MI; i++){
#pragma unroll
    for (int j = 0; j < 4; j++){
#pragma unroll
      for (int r = 0; r < 4; r++){
        int orow = brow + wr + i * 16 + (lane >> 4) * 4 + r;
        int ocol = bcol + wc + j * 16 + l15;
        size_t oi = (size_t)orow * N + ocol;
        float v = acc[i][j][r];
        if constexpr (EPI == 2){
          float ls = (v >= 0.f) ? -log1pf(__expf(-v)) : (v - log1pf(__expf(v)));
          ((float*)out0)[oi] = ls * 0.125f;
        } else {
          ((float*)out0)[oi] = v;
        }
      }
    }
  }
}

// ---------------------------------------------------------------- pass A
__global__ __launch_bounds__(256, 3) void k_pass_a(
    const u16* __restrict__ kb, u16* __restrict__ vb,
    const float* __restrict__ gbuf,
    u16* __restrict__ UkT, u16* __restrict__ UvT, float* __restrict__ Alast,
    float* __restrict__ cumbuf)
{
  __shared__ u16 ShT[64 * 72];
  __shared__ u16 KV[256 * 72];
  __shared__ float qsum[256];
  const int bc = blockIdx.x;
  const int bh = bc >> 5, c = bc & 31;
  const int b = bh >> 2, h = bh & 3;
  const int row0 = b * 2048 + c * 64;
  const int tid = threadIdx.x;
  const int lane = tid & 63, wv = tid >> 6;
  const int l15 = lane & 15, koff = (lane >> 4) * 8;
  const int qseg = tid >> 6, m = tid & 63;
  const int ti0  = (tid & 15) * 4;
  const int tkd0 = (tid >> 4) * 4;

  ushort4 kpre[16];
#pragma unroll
  for (int it = 0; it < 4; it++)
#pragma unroll
    for (int cc = 0; cc < 4; cc++)
      kpre[it*4+cc] = *reinterpret_cast<const ushort4*>(
          kb + (size_t)(row0 + ti0 + cc) * QS + h * 256 + tkd0 + it * 64);

  float gr[16];
#pragma unroll
  for (int j = 0; j < 16; j++)
    gr[j] = gbuf[(size_t)(row0 + qseg * 16 + j) * 256 + h * 64 + m];
  float part = 0.f;
#pragma unroll
  for (int j = 0; j < 16; j++) part += gr[j];
  qsum[qseg * 64 + m] = part;
  __syncthreads();
  float run = 0.f, tot = 0.f;
#pragma unroll
  for (int jj = 0; jj < 4; jj++){
    float v = qsum[jj * 64 + m];
    tot += v;
    if (jj < qseg) run += v;
  }
  float ec63 = __expf(tot);
  if (qseg == 0) Alast[(size_t)bc * 64 + m] = ec63;
#pragma unroll
  for (int j = 0; j < 16; j++){
    run += gr[j];
    int i = qseg * 16 + j;
    float en = __expf(-run);
    float sv = 1.f - __expf(gr[j]);
    float pre = sv * en;
    cumbuf[(size_t)bc * 4096 + i * 64 + m] = run;
    ShT[m * 72 + i] = f2bf(pre * ec63);
  }

#pragma unroll
  for (int it = 0; it < 4; it++){
    int kd0 = tkd0 + it * 64;
#pragma unroll
    for (int d = 0; d < 4; d++){
      ushort4 w;
      w.x = u4get(kpre[it*4+0], d); w.y = u4get(kpre[it*4+1], d);
      w.z = u4get(kpre[it*4+2], d); w.w = u4get(kpre[it*4+3], d);
      *reinterpret_cast<ushort4*>(&KV[(size_t)(kd0 + d) * 72 + ti0]) = w;
    }
  }
  ushort4 vpre[16];
#pragma unroll
  for (int it = 0; it < 4; it++)
#pragma unroll
    for (int cc = 0; cc < 4; cc++)
      vpre[it*4+cc] = *reinterpret_cast<const ushort4*>(
          vb + (size_t)(row0 + ti0 + cc) * QS + h * 256 + tkd0 + it * 64);
  __syncthreads();

  { // U_kT
    f32x4 acc[16];
#pragma unroll
    for (int n = 0; n < 16; n++) acc[n] = f32x4{0.f, 0.f, 0.f, 0.f};
#pragma unroll
    for (int ks = 0; ks < 2; ks++){
      bf16x8 a = ldfrag(&ShT[(wv * 16 + l15) * 72 + ks * 32 + koff]);
#pragma unroll
      for (int n = 0; n < 16; n++){
        bf16x8 bb = ldfrag(&KV[(n * 16 + l15) * 72 + ks * 32 + koff]);
        acc[n] = mfma16(a, bb, acc[n]);
      }
    }
#pragma unroll
    for (int n = 0; n < 16; n++)
#pragma unroll
      for (int r = 0; r < 4; r++){
        int mm = wv * 16 + (lane >> 4) * 4 + r;
        UkT[((size_t)bc * 64 + mm) * 256 + n * 16 + l15] = f2bf(acc[n][r]);
      }
  }
  __syncthreads();

#pragma unroll
  for (int it = 0; it < 4; it++){
    int kd0 = tkd0 + it * 64;
#pragma unroll
    for (int d = 0; d < 4; d++){
      int vd = kd0 + d;
      ushort4 w;
      w.x = u4get(vpre[it*4+0], d); w.y = u4get(vpre[it*4+1], d);
      w.z = u4get(vpre[it*4+2], d); w.w = u4get(vpre[it*4+3], d);
      *reinterpret_cast<ushort4*>(&KV[(size_t)vd * 72 + ti0]) = w;
      *reinterpret_cast<ushort4*>(
          vb + (size_t)(row0 + (vd >> 2)) * QS + h * 256 + (vd & 3) * 64 + ti0) = w;
    }
  }
  __syncthreads();

  { // U_vT
    f32x4 acc[4][4];
#pragma unroll
    for (int i = 0; i < 4; i++)
#pragma unroll
      for (int j = 0; j < 4; j++) acc[i][j] = f32x4{0.f, 0.f, 0.f, 0.f};
#pragma unroll
    for (int ks = 0; ks < 2; ks++){
      bf16x8 a[4], bb[4];
#pragma unroll
      for (int mt = 0; mt < 4; mt++)
        a[mt] = ldfrag(&KV[(wv * 64 + mt * 16 + l15) * 72 + ks * 32 + koff]);
#pragma unroll
      for (int nt = 0; nt < 4; nt++)
        bb[nt] = ldfrag(&ShT[(nt * 16 + l15) * 72 + ks * 32 + koff]);
#pragma unroll
      for (int mt = 0; mt < 4; mt++)
#pragma unroll
        for (int nt = 0; nt < 4; nt++)
          acc[mt][nt] = mfma16(a[mt], bb[nt], acc[mt][nt]);
    }
#pragma unroll
    for (int mt = 0; mt < 4; mt++)
#pragma unroll
      for (int nt = 0; nt < 4; nt++)
#pragma unroll
        for (int r = 0; r < 4; r++){
          int vd = wv * 64 + mt * 16 + (lane >> 4) * 4 + r;
          UvT[((size_t)bc * 256 + vd) * 64 + nt * 16 + l15] = f2bf(acc[mt][nt][r]);
        }
  }
}

// ---------------------------------------------------------------- pass B
__global__ __launch_bounds__(256) void k_pass_b(
    u16* __restrict__ UkT, u16* __restrict__ UvT, const float* __restrict__ Alast)
{
  const int blk  = blockIdx.x;
  const int bh   = blk >> 5;
  const int slab = blk & 31;
  const int tid  = threadIdx.x;
  const bool isV = slab >= 16;
  u16* U = isV ? UvT : UkT;
  const int e0 = (slab & 15) * 1024 + tid * 4;
  const size_t base = (size_t)bh * 32 * 16384 + e0;
  const float* alb = Alast + (size_t)bh * 32 * 64;
  const int mK = e0 >> 8;
  const int mV = e0 & 63;

  float h0 = 0.f, h1 = 0.f, h2 = 0.f, h3 = 0.f;
  ushort4 u0 = *reinterpret_cast<ushort4*>(&U[base]);
  ushort4 u1 = *reinterpret_cast<ushort4*>(&U[base + 16384]);
  for (int c = 0; c < 32; c++){
    const int cn = (c + 2 < 32) ? c + 2 : 31;
    ushort4 u2 = *reinterpret_cast<ushort4*>(&U[base + (size_t)cn * 16384]);
    float a0, a1, a2, a3;
    if (isV){
      float4 av = *reinterpret_cast<const float4*>(alb + c * 64 + mV);
      a0 = av.x; a1 = av.y; a2 = av.z; a3 = av.w;
    } else {
      float av = alb[c * 64 + mK];
      a0 = a1 = a2 = a3 = av;
    }
    ushort4 s;
    s.x = f2bf(h0); s.y = f2bf(h1); s.z = f2bf(h2); s.w = f2bf(h3);
    *reinterpret_cast<ushort4*>(&U[base + (size_t)c * 16384]) = s;
    h0 = h0 * a0 + bf2f(u0.x);
    h1 = h1 * a1 + bf2f(u0.y);
    h2 = h2 * a2 + bf2f(u0.z);
    h3 = h3 * a3 + bf2f(u0.w);
    u0 = u1; u1 = u2;
  }
}

// ---------------------------------------------------------------- pass C
__global__ __launch_bounds__(256, 4) void k_pass_c(
    const u16* __restrict__ qb, const u16* __restrict__ kb, const u16* __restrict__ vb,
    const float* __restrict__ gbuf, const float* __restrict__ cumbuf,
    const u16* __restrict__ hk0T, const u16* __restrict__ hv0T,
    const float* __restrict__ gnw, u16* __restrict__ omid)
{
  __shared__ u16 Sh [64 * 72];
  __shared__ u16 ShT[64 * 72];
  __shared__ u16 QKm[64 * 72];
  __shared__ u16 Pt [64 * 72];
  const int bc = blockIdx.x;
  const int bh = bc >> 5, c = bc & 31;
  const int b = bh >> 2, h = bh & 3;
  const int row0 = b * 2048 + c * 64;
  const int tid = threadIdx.x, lane = tid & 63, wv = tid >> 6;
  const int l15 = lane & 15, koff = (lane >> 4) * 8;
  const int irow = wv * 16;
  const int ti0  = (tid & 15) * 4;
  const int tkd0 = (tid >> 4) * 4;

  bf16x8 qf[8];
#pragma unroll
  for (int ks = 0; ks < 8; ks++)
    qf[ks] = ldfrag(qb + (size_t)(row0 + irow + l15) * QS + h * 256 + ks * 32 + koff);
  float4 gq[4], cq[4];
#pragma unroll
  for (int cc = 0; cc < 4; cc++){
    gq[cc] = *reinterpret_cast<const float4*>(
        &gbuf[(size_t)(row0 + ti0 + cc) * 256 + h * 64 + tkd0]);
    cq[cc] = *reinterpret_cast<const float4*>(
        &cumbuf[(size_t)bc * 4096 + (ti0 + cc) * 64 + tkd0]);
  }
  float cumv[4][4];
#pragma unroll
  for (int nt = 0; nt < 4; nt++)
#pragma unroll
    for (int r = 0; r < 4; r++)
      cumv[nt][r] = cumbuf[(size_t)bc * 4096 +
                           (irow + (lane >> 4) * 4 + r) * 64 + nt * 16 + l15];

  f32x4 lac[4];
  {
    f32x4 qk[4];
#pragma unroll
    for (int n = 0; n < 4; n++){ qk[n] = f32x4{0.f, 0.f, 0.f, 0.f}; lac[n] = f32x4{0.f, 0.f, 0.f, 0.f}; }
#pragma unroll
    for (int ks = 0; ks < 8; ks++){
#pragma unroll
      for (int nt = 0; nt < 4; nt++){
        bf16x8 bb = ldfrag(kb + (size_t)(row0 + nt * 16 + l15) * QS + h * 256 + ks * 32 + koff);
        qk[nt] = mfma16(qf[ks], bb, qk[nt]);
      }
#pragma unroll
      for (int nt = 0; nt < 4; nt++){
        bf16x8 bh0 = ldfrag(hk0T + ((size_t)bc * 64 + nt * 16 + l15) * 256 + ks * 32 + koff);
        lac[nt] = mfma16(qf[ks], bh0, lac[nt]);
      }
    }
#pragma unroll
    for (int nt = 0; nt < 4; nt++)
#pragma unroll
      for (int r = 0; r < 4; r++){
        int i = irow + (lane >> 4) * 4 + r;
        int j = nt * 16 + l15;
        QKm[i * 72 + j] = f2bf((j <= i) ? qk[nt][r] : 0.f);
      }
  }

  u16 shv[4][4];
#pragma unroll
  for (int cc = 0; cc < 4; cc++){
#pragma unroll
    for (int d = 0; d < 4; d++){
      float pre = (1.f - __expf(f4get(gq[cc], d))) * __expf(-f4get(cq[cc], d));
      shv[cc][d] = f2bf(pre);
    }
    ushort4 w; w.x = shv[cc][0]; w.y = shv[cc][1]; w.z = shv[cc][2]; w.w = shv[cc][3];
    *reinterpret_cast<ushort4*>(&Sh[(ti0 + cc) * 72 + tkd0]) = w;
  }
#pragma unroll
  for (int d = 0; d < 4; d++){
    ushort4 w; w.x = shv[0][d]; w.y = shv[1][d]; w.z = shv[2][d]; w.w = shv[3][d];
    *reinterpret_cast<ushort4*>(&ShT[(tkd0 + d) * 72 + ti0]) = w;
  }
  float ai[4][4];
#pragma unroll
  for (int nt = 0; nt < 4; nt++)
#pragma unroll
    for (int r = 0; r < 4; r++)
      ai[nt][r] = __expf(cumv[nt][r]);

  __syncthreads();

  {
#pragma unroll
    for (int ks = 0; ks < 2; ks++){
      bf16x8 a = ldfrag(&QKm[(irow + l15) * 72 + ks * 32 + koff]);
#pragma unroll
      for (int nt = 0; nt < 4; nt++){
        bf16x8 bb = ldfrag(&ShT[(nt * 16 + l15) * 72 + ks * 32 + koff]);
        lac[nt] = mfma16(a, bb, lac[nt]);
      }
    }
#pragma unroll
    for (int r = 0; r < 4; r++){
      int i = irow + (lane >> 4) * 4 + r;
      float Lv[4];
      float mx = -3.4e38f;
#pragma unroll
      for (int nt = 0; nt < 4; nt++){
        Lv[nt] = ai[nt][r] * 0.0625f * lac[nt][r];
        mx = fmaxf(mx, Lv[nt]);
      }
#pragma unroll
      for (int d = 1; d < 16; d <<= 1) mx = fmaxf(mx, __shfl_xor(mx, d, 16));
      float sum = 0.f;
#pragma unroll
      for (int nt = 0; nt < 4; nt++){ Lv[nt] = __expf(Lv[nt] - mx); sum += Lv[nt]; }
#pragma unroll
      for (int d = 1; d < 16; d <<= 1) sum += __shfl_xor(sum, d, 16);
      float inv = 1.f / sum;
#pragma unroll
      for (int nt = 0; nt < 4; nt++)
        Pt[i * 72 + nt * 16 + l15] = f2bf(Lv[nt] * inv * ai[nt][r]);
    }
  }

  {
    f32x4 wac[4];
#pragma unroll
    for (int n = 0; n < 4; n++) wac[n] = f32x4{0.f, 0.f, 0.f, 0.f};
#pragma unroll
    for (int ks = 0; ks < 2; ks++){
      bf16x8 a = ldfrag(&Pt[(irow + l15) * 72 + ks * 32 + koff]);
#pragma unroll
      for (int nt = 0; nt < 4; nt++){
        bf16x8 bb = ldfrag(&Sh[(nt * 16 + l15) * 72 + ks * 32 + koff]);
        wac[nt] = mfma16(a, bb, wac[nt]);
      }
    }
#pragma unroll
    for (int nt = 0; nt < 4; nt++)
#pragma unroll
      for (int r = 0; r < 4; r++){
        int i = irow + (lane >> 4) * 4 + r;
        int j = nt * 16 + l15;
        QKm[i * 72 + j] = f2bf((j <= i) ? wac[nt][r] : 0.f);
      }
  }

  {
    f32x4 oac[16];
#pragma unroll
    for (int n = 0; n < 16; n++) oac[n] = f32x4{0.f, 0.f, 0.f, 0.f};
#pragma unroll
    for (int ks = 0; ks < 2; ks++){
      bf16x8 a = ldfrag(&Pt[(irow + l15) * 72 + ks * 32 + koff]);
#pragma unroll
      for (int nt = 0; nt < 16; nt++){
        bf16x8 bb = ldfrag(hv0T + ((size_t)bc * 256 + nt * 16 + l15) * 64 + ks * 32 + koff);
        oac[nt] = mfma16(a, bb, oac[nt]);
      }
    }
#pragma unroll
    for (int ks = 0; ks < 2; ks++){
      bf16x8 a = ldfrag(&QKm[(irow + l15) * 72 + ks * 32 + koff]);
#pragma unroll
      for (int nt = 0; nt < 16; nt++){
        int vd = nt * 16 + l15;
        bf16x8 bb = ldfrag(vb + (size_t)(row0 + (vd >> 2)) * QS + h * 256
                              + (vd & 3) * 64 + ks * 32 + koff);
        oac[nt] = mfma16(a, bb, oac[nt]);
      }
    }
    float gn[16];
#pragma unroll
    for (int nt = 0; nt < 16; nt++) gn[nt] = gnw[nt * 16 + l15];
#pragma unroll
    for (int r = 0; r < 4; r++){
      float ss = 0.f;
#pragma unroll
      for (int nt = 0; nt < 16; nt++) ss += oac[nt][r] * oac[nt][r];
#pragma unroll
      for (int d = 1; d < 16; d <<= 1) ss += __shfl_xor(ss, d, 16);
      float rin = rsqrtf(ss * (1.f / 256.f) + 1e-5f);
      int i = irow + (lane >> 4) * 4 + r;
#pragma unroll
      for (int nt = 0; nt < 16; nt++)
        omid[(size_t)(row0 + i) * 1024 + h * 256 + nt * 16 + l15] = f2bf(oac[nt][r] * rin * gn[nt]);
    }
  }
}

// ---------------------------------------------------------------- launch
extern "C" void kernel_launch(void* const* d_in, const int* in_sizes, int n_in,
                              void* d_out, int out_size, void* d_ws, size_t ws_size,
                              hipStream_t stream)
{
  const float* x   = (const float*)d_in[0];
  const float* Wq  = (const float*)d_in[1];
  const float* Wk  = (const float*)d_in[2];
  const float* Wv  = (const float*)d_in[3];
  const float* Wf  = (const float*)d_in[4];
  const float* gnw = (const float*)d_in[5];
  const float* Wo  = (const float*)d_in[6];
  float* out = (float*)d_out;

  char* w = (char*)d_ws;
  size_t off = 0;
  auto alloc = [&](size_t bytes)->char*{
    char* p = w + off; off += (bytes + 255) & ~(size_t)255; return p;
  };
  u16*  xb     = (u16*)alloc(8192ULL * 1024 * 2);   // later reused as o_mid
  u16*  wqkvT  = (u16*)alloc(3072ULL * 1024 * 2);   // [WqT;WkT;WvT]
  u16*  woT    = (u16*)alloc(1024ULL * 1024 * 2);
  u16*  wfT    = (u16*)alloc(256ULL  * 1024 * 2);
  u16*  qkv    = (u16*)alloc(8192ULL * 3072 * 2);   // fused q|k|v, stride 3072
  float* gbuf  = (float*)alloc(8192ULL * 256 * 4);
  u16*  UkT    = (u16*)alloc(512ULL * 64 * 256 * 2);  // becomes hk0 snapshots
  u16*  UvT    = (u16*)alloc(512ULL * 256 * 64 * 2);  // becomes hv0 snapshots
  float* alast = (float*)alloc(512ULL * 64 * 4);
  float* cumbuf= (float*)alloc(512ULL * 4096 * 4);
  if (ws_size < off) return;

  dim3 tb(32, 8);
  k_prep<<<dim3(32, 32, 13), tb, 0, stream>>>(
      x, xb, Wq, Wk, Wv, Wo, Wf,
      wqkvT, wqkvT + 1024ULL*1024, wqkvT + 2048ULL*1024, woT, wfT);

  // fused q|k|v projection on the 256^2 deep-pipelined template
  k_gemm256<4><<<dim3(32, 12), 512, 0, stream>>>(xb, wqkvT, 3072, qkv);
  k_gemm<2, 64><<<dim3(128, 2), 256, 0, stream>>>(xb, wfT, 1024, 256, gbuf);

  k_pass_a<<<512, 256, 0, stream>>>(qkv + 1024, qkv + 2048, gbuf, UkT, UvT, alast, cumbuf);
  k_pass_b<<<512, 256, 0, stream>>>(UkT, UvT, alast);
  k_pass_c<<<512, 256, 0, stream>>>(qkv, qkv + 1024, qkv + 2048, gbuf, cumbuf,
                                    UkT, UvT, gnw, xb);

  k_gemm256<3><<<dim3(32, 4), 512, 0, stream>>>(xb, woT, 1024, out);
}

// Round 13
// 224.493 us; speedup vs baseline: 1.1872x; 1.1872x over previous
//
#include <hip/hip_runtime.h>
#include <hip/hip_bf16.h>
#include <stdint.h>

typedef unsigned short u16;
typedef __attribute__((ext_vector_type(8))) __bf16 bf16x8;
typedef __attribute__((ext_vector_type(4))) float f32x4;

#define QS 3072   // row stride of fused qkv buffer

#define DEV static __device__ __forceinline__

DEV u16 f2bf(float f){
  __hip_bfloat16 h = __float2bfloat16(f);
  return *reinterpret_cast<u16*>(&h);
}
DEV float bf2f(u16 u){
  __hip_bfloat16 h;
  *reinterpret_cast<u16*>(&h) = u;
  return __bfloat162float(h);
}
DEV f32x4 mfma16(bf16x8 a, bf16x8 b, f32x4 c){
  return __builtin_amdgcn_mfma_f32_16x16x32_bf16(a, b, c, 0, 0, 0);
}
DEV bf16x8 ldfrag(const u16* p){ return *reinterpret_cast<const bf16x8*>(p); }
DEV u16 u4get(ushort4 v, int d){ return d==0?v.x: d==1?v.y: d==2?v.z: v.w; }
DEV float f4get(float4 v, int d){ return d==0?v.x: d==1?v.y: d==2?v.z: v.w; }

DEV void gl_lds16(const u16* g, u16* l){
  __builtin_amdgcn_global_load_lds(
      (const __attribute__((address_space(1))) void*)g,
      (__attribute__((address_space(3))) void*)l, 16, 0, 0);
}

// counted-vmcnt barrier (T4): keep next tile's loads in flight across barrier
template<int N> DEV void wait_barrier(){
  if constexpr (N == 0)      asm volatile("s_waitcnt vmcnt(0)\ns_barrier" ::: "memory");
  else if constexpr (N == 3) asm volatile("s_waitcnt vmcnt(3)\ns_barrier" ::: "memory");
  else                       asm volatile("s_waitcnt vmcnt(4)\ns_barrier" ::: "memory");
}

// ---------------------------------------------------------------- prep
// Merged: z<5 -> weight transposes (Wq/Wk/Wv/Wo [1024x1024], Wf [1024x256]);
// z>=5 -> x fp32->bf16 convert (8192 logical blocks).
__global__ void k_prep(const float* __restrict__ x, u16* __restrict__ xb,
                       const float* __restrict__ s0, const float* __restrict__ s1,
                       const float* __restrict__ s2, const float* __restrict__ s3,
                       const float* __restrict__ s4,
                       u16* __restrict__ d0, u16* __restrict__ d1,
                       u16* __restrict__ d2, u16* __restrict__ d3,
                       u16* __restrict__ d4){
  const int z = blockIdx.z;
  if (z >= 5){
    int lb  = (z - 5) * 1024 + blockIdx.y * 32 + blockIdx.x;
    int tid = threadIdx.y * 32 + threadIdx.x;
    size_t i = ((size_t)lb * 256 + tid) * 4;
    float4 v = *reinterpret_cast<const float4*>(x + i);
    ushort4 o;
    o.x = f2bf(v.x); o.y = f2bf(v.y); o.z = f2bf(v.z); o.w = f2bf(v.w);
    *reinterpret_cast<ushort4*>(xb + i) = o;
    return;
  }
  const float* src = (z==0)?s0:(z==1)?s1:(z==2)?s2:(z==3)?s3:s4;
  u16* dst = (z==0)?d0:(z==1)?d1:(z==2)?d2:(z==3)?d3:d4;
  const int C = (z==4) ? 256 : 1024;
  int bx = blockIdx.x * 32, by = blockIdx.y * 32;
  if (bx >= C) return;
  __shared__ u16 t[32][33];
  int tx = threadIdx.x;
  for (int dy = threadIdx.y; dy < 32; dy += 8)
    t[dy][tx] = f2bf(src[(size_t)(by + dy) * C + bx + tx]);
  __syncthreads();
  for (int dy = threadIdx.y; dy < 32; dy += 8)
    dst[(size_t)(bx + dy) * 1024 + by + tx] = t[tx][dy];
}

// ---------------------------------------------------------------- GEMM
// BMx128 tile, 4 waves, 3-deep LDS pipeline with counted vmcnt.
// T3 recipe order: stage(t+2) issued FIRST (right after the barrier), then
// ds_read+MFMA -- doubles prefetch distance to ~2 iterations.
// T2: st_16x32 XOR swizzle both-sides (pre-swizzled global src + swizzled
// ds_read col; LDS dest linear for global_load_lds). Conflicts measured 0.
// EPI: 2=gate f fp32, 3=fp32, 4=qkv (cols<2048 swish; bf16, single dest)
template<int EPI, int BM>
__global__ __launch_bounds__(256) void k_gemm(
    const u16* __restrict__ A, const u16* __restrict__ BT,
    int K, int N, void* __restrict__ out0)
{
  __shared__ u16 As[3][BM * 32];
  __shared__ u16 Bs[3][128 * 32];
  const int tid  = threadIdx.x;
  const int lane = tid & 63;
  const int wv   = tid >> 6;
  // per-XCD brow-chunk swizzle (requires gridDim.x % 8 == 0)
  const int gx  = gridDim.x;
  const int npx = gx >> 3;
  const int lin = blockIdx.y * gx + blockIdx.x;
  const int xcd = lin & 7;
  const int idx = lin >> 3;
  const int brow = (xcd * npx + (idx % npx)) * BM;
  const int bcol = (idx / npx) * 128;
  const int wr   = (wv >> 1) * (BM / 2);
  const int wc   = (wv & 1) * 64;
  const int l15  = lane & 15;
  const int koff = (lane >> 4) * 8;
  const int lr   = lane >> 2;
  const int lc8  = (lane & 3) * 8;
  const int lc8s = lc8 ^ (((lr >> 3) & 1) << 4);
  const int ksw  = koff ^ (((l15 >> 3) & 1) << 4);
  constexpr int MI = BM / 32;
  constexpr int LPS = (BM == 128) ? 4 : 3;

  f32x4 acc[MI][4];
#pragma unroll
  for (int i = 0; i < MI; i++)
#pragma unroll
    for (int j = 0; j < 4; j++) acc[i][j] = f32x4{0.f, 0.f, 0.f, 0.f};

  auto stage = [&](int buf, int kt){
    if constexpr (BM == 128){
#pragma unroll
      for (int j = 0; j < 2; j++){
        int rb = wv * 32 + j * 16;
        gl_lds16(A  + (size_t)(brow + rb + lr) * K + kt + lc8s, &As[buf][rb * 32]);
        gl_lds16(BT + (size_t)(bcol + rb + lr) * K + kt + lc8s, &Bs[buf][rb * 32]);
      }
    } else {
      gl_lds16(A + (size_t)(brow + wv * 16 + lr) * K + kt + lc8s, &As[buf][wv * 16 * 32]);
#pragma unroll
      for (int j = 0; j < 2; j++){
        int rb = wv * 32 + j * 16;
        gl_lds16(BT + (size_t)(bcol + rb + lr) * K + kt + lc8s, &Bs[buf][rb * 32]);
      }
    }
  };

  const int nit = K >> 5;
  stage(0, 0);
  stage(1, 32);
  for (int it = 0; it < nit; it++){
    const int cur = it % 3;
    if (it + 1 < nit) wait_barrier<LPS>();
    else              wait_barrier<0>();
    if (it + 2 < nit) stage((it + 2) % 3, (it + 2) << 5);  // T3: issue loads FIRST
    bf16x8 af[MI], bfv[4];
#pragma unroll
    for (int i = 0; i < MI; i++) af[i]  = ldfrag(&As[cur][(wr + i * 16 + l15) * 32 + ksw]);
#pragma unroll
    for (int j = 0; j < 4; j++) bfv[j] = ldfrag(&Bs[cur][(wc + j * 16 + l15) * 32 + ksw]);
#pragma unroll
    for (int i = 0; i < MI; i++)
#pragma unroll
      for (int j = 0; j < 4; j++)
        acc[i][j] = mfma16(af[i], bfv[j], acc[i][j]);
  }

#pragma unroll
  for (int i = 0; i < MI; i++){
#pragma unroll
    for (int j = 0; j < 4; j++){
#pragma unroll
      for (int r = 0; r < 4; r++){
        int orow = brow + wr + i * 16 + (lane >> 4) * 4 + r;
        int ocol = bcol + wc + j * 16 + l15;
        size_t oi = (size_t)orow * N + ocol;
        float v = acc[i][j][r];
        if constexpr (EPI == 2){
          float ls = (v >= 0.f) ? -log1pf(__expf(-v)) : (v - log1pf(__expf(v)));
          ((float*)out0)[oi] = ls * 0.125f;          // f = log_sigmoid/8
        } else if constexpr (EPI == 3){
          ((float*)out0)[oi] = v;
        } else {                                      // EPI == 4: fused qkv
          float o = (bcol < 2048) ? v / (1.f + __expf(-v)) : v;
          ((u16*)out0)[oi] = f2bf(o);
        }
      }
    }
  }
}

// ---------------------------------------------------------------- pass A
// Register-resident cumsum; writes cumbuf f32; K^T/V^T staged via 4x4
// register transpose; V^T also written back into the consumed v-region of qkv.
__global__ __launch_bounds__(256, 3) void k_pass_a(
    const u16* __restrict__ kb, u16* __restrict__ vb,
    const float* __restrict__ gbuf,
    u16* __restrict__ UkT, u16* __restrict__ UvT, float* __restrict__ Alast,
    float* __restrict__ cumbuf)
{
  __shared__ u16 ShT[64 * 72];
  __shared__ u16 KV[256 * 72];
  __shared__ float qsum[256];
  const int bc = blockIdx.x;
  const int bh = bc >> 5, c = bc & 31;
  const int b = bh >> 2, h = bh & 3;
  const int row0 = b * 2048 + c * 64;
  const int tid = threadIdx.x;
  const int lane = tid & 63, wv = tid >> 6;
  const int l15 = lane & 15, koff = (lane >> 4) * 8;
  const int qseg = tid >> 6, m = tid & 63;
  const int ti0  = (tid & 15) * 4;
  const int tkd0 = (tid >> 4) * 4;

  ushort4 kpre[16];
#pragma unroll
  for (int it = 0; it < 4; it++)
#pragma unroll
    for (int cc = 0; cc < 4; cc++)
      kpre[it*4+cc] = *reinterpret_cast<const ushort4*>(
          kb + (size_t)(row0 + ti0 + cc) * QS + h * 256 + tkd0 + it * 64);

  float gr[16];
#pragma unroll
  for (int j = 0; j < 16; j++)
    gr[j] = gbuf[(size_t)(row0 + qseg * 16 + j) * 256 + h * 64 + m];
  float part = 0.f;
#pragma unroll
  for (int j = 0; j < 16; j++) part += gr[j];
  qsum[qseg * 64 + m] = part;
  __syncthreads();
  float run = 0.f, tot = 0.f;
#pragma unroll
  for (int jj = 0; jj < 4; jj++){
    float v = qsum[jj * 64 + m];
    tot += v;
    if (jj < qseg) run += v;
  }
  float ec63 = __expf(tot);
  if (qseg == 0) Alast[(size_t)bc * 64 + m] = ec63;
#pragma unroll
  for (int j = 0; j < 16; j++){
    run += gr[j];
    int i = qseg * 16 + j;
    float en = __expf(-run);
    float sv = 1.f - __expf(gr[j]);
    float pre = sv * en;
    cumbuf[(size_t)bc * 4096 + i * 64 + m] = run;
    ShT[m * 72 + i] = f2bf(pre * ec63);
  }

#pragma unroll
  for (int it = 0; it < 4; it++){
    int kd0 = tkd0 + it * 64;
#pragma unroll
    for (int d = 0; d < 4; d++){
      ushort4 w;
      w.x = u4get(kpre[it*4+0], d); w.y = u4get(kpre[it*4+1], d);
      w.z = u4get(kpre[it*4+2], d); w.w = u4get(kpre[it*4+3], d);
      *reinterpret_cast<ushort4*>(&KV[(size_t)(kd0 + d) * 72 + ti0]) = w;
    }
  }
  ushort4 vpre[16];
#pragma unroll
  for (int it = 0; it < 4; it++)
#pragma unroll
    for (int cc = 0; cc < 4; cc++)
      vpre[it*4+cc] = *reinterpret_cast<const ushort4*>(
          vb + (size_t)(row0 + ti0 + cc) * QS + h * 256 + tkd0 + it * 64);
  __syncthreads();

  { // U_kT
    f32x4 acc[16];
#pragma unroll
    for (int n = 0; n < 16; n++) acc[n] = f32x4{0.f, 0.f, 0.f, 0.f};
#pragma unroll
    for (int ks = 0; ks < 2; ks++){
      bf16x8 a = ldfrag(&ShT[(wv * 16 + l15) * 72 + ks * 32 + koff]);
#pragma unroll
      for (int n = 0; n < 16; n++){
        bf16x8 bb = ldfrag(&KV[(n * 16 + l15) * 72 + ks * 32 + koff]);
        acc[n] = mfma16(a, bb, acc[n]);
      }
    }
#pragma unroll
    for (int n = 0; n < 16; n++)
#pragma unroll
      for (int r = 0; r < 4; r++){
        int mm = wv * 16 + (lane >> 4) * 4 + r;
        UkT[((size_t)bc * 64 + mm) * 256 + n * 16 + l15] = f2bf(acc[n][r]);
      }
  }
  __syncthreads();

#pragma unroll
  for (int it = 0; it < 4; it++){
    int kd0 = tkd0 + it * 64;
#pragma unroll
    for (int d = 0; d < 4; d++){
      int vd = kd0 + d;
      ushort4 w;
      w.x = u4get(vpre[it*4+0], d); w.y = u4get(vpre[it*4+1], d);
      w.z = u4get(vpre[it*4+2], d); w.w = u4get(vpre[it*4+3], d);
      *reinterpret_cast<ushort4*>(&KV[(size_t)vd * 72 + ti0]) = w;
      *reinterpret_cast<ushort4*>(
          vb + (size_t)(row0 + (vd >> 2)) * QS + h * 256 + (vd & 3) * 64 + ti0) = w;
    }
  }
  __syncthreads();

  { // U_vT
    f32x4 acc[4][4];
#pragma unroll
    for (int i = 0; i < 4; i++)
#pragma unroll
      for (int j = 0; j < 4; j++) acc[i][j] = f32x4{0.f, 0.f, 0.f, 0.f};
#pragma unroll
    for (int ks = 0; ks < 2; ks++){
      bf16x8 a[4], bb[4];
#pragma unroll
      for (int mt = 0; mt < 4; mt++)
        a[mt] = ldfrag(&KV[(wv * 64 + mt * 16 + l15) * 72 + ks * 32 + koff]);
#pragma unroll
      for (int nt = 0; nt < 4; nt++)
        bb[nt] = ldfrag(&ShT[(nt * 16 + l15) * 72 + ks * 32 + koff]);
#pragma unroll
      for (int mt = 0; mt < 4; mt++)
#pragma unroll
        for (int nt = 0; nt < 4; nt++)
          acc[mt][nt] = mfma16(a[mt], bb[nt], acc[mt][nt]);
    }
#pragma unroll
    for (int mt = 0; mt < 4; mt++)
#pragma unroll
      for (int nt = 0; nt < 4; nt++)
#pragma unroll
        for (int r = 0; r < 4; r++){
          int vd = wv * 64 + mt * 16 + (lane >> 4) * 4 + r;
          UvT[((size_t)bc * 256 + vd) * 64 + nt * 16 + l15] = f2bf(acc[mt][nt][r]);
        }
  }
}

// ---------------------------------------------------------------- pass B
__global__ __launch_bounds__(256) void k_pass_b(
    u16* __restrict__ UkT, u16* __restrict__ UvT, const float* __restrict__ Alast)
{
  const int blk  = blockIdx.x;
  const int bh   = blk >> 5;
  const int slab = blk & 31;
  const int tid  = threadIdx.x;
  const bool isV = slab >= 16;
  u16* U = isV ? UvT : UkT;
  const int e0 = (slab & 15) * 1024 + tid * 4;
  const size_t base = (size_t)bh * 32 * 16384 + e0;
  const float* alb = Alast + (size_t)bh * 32 * 64;
  const int mK = e0 >> 8;
  const int mV = e0 & 63;

  float h0 = 0.f, h1 = 0.f, h2 = 0.f, h3 = 0.f;
  ushort4 u0 = *reinterpret_cast<ushort4*>(&U[base]);
  ushort4 u1 = *reinterpret_cast<ushort4*>(&U[base + 16384]);
  for (int c = 0; c < 32; c++){
    const int cn = (c + 2 < 32) ? c + 2 : 31;
    ushort4 u2 = *reinterpret_cast<ushort4*>(&U[base + (size_t)cn * 16384]);
    float a0, a1, a2, a3;
    if (isV){
      float4 av = *reinterpret_cast<const float4*>(alb + c * 64 + mV);
      a0 = av.x; a1 = av.y; a2 = av.z; a3 = av.w;
    } else {
      float av = alb[c * 64 + mK];
      a0 = a1 = a2 = a3 = av;
    }
    ushort4 s;
    s.x = f2bf(h0); s.y = f2bf(h1); s.z = f2bf(h2); s.w = f2bf(h3);
    *reinterpret_cast<ushort4*>(&U[base + (size_t)c * 16384]) = s;
    h0 = h0 * a0 + bf2f(u0.x);
    h1 = h1 * a1 + bf2f(u0.y);
    h2 = h2 * a2 + bf2f(u0.z);
    h3 = h3 * a3 + bf2f(u0.w);
    u0 = u1; u1 = u2;
  }
}

// ---------------------------------------------------------------- pass C
__global__ __launch_bounds__(256, 4) void k_pass_c(
    const u16* __restrict__ qb, const u16* __restrict__ kb, const u16* __restrict__ vb,
    const float* __restrict__ gbuf, const float* __restrict__ cumbuf,
    const u16* __restrict__ hk0T, const u16* __restrict__ hv0T,
    const float* __restrict__ gnw, u16* __restrict__ omid)
{
  __shared__ u16 Sh [64 * 72];
  __shared__ u16 ShT[64 * 72];
  __shared__ u16 QKm[64 * 72];
  __shared__ u16 Pt [64 * 72];
  const int bc = blockIdx.x;
  const int bh = bc >> 5, c = bc & 31;
  const int b = bh >> 2, h = bh & 3;
  const int row0 = b * 2048 + c * 64;
  const int tid = threadIdx.x, lane = tid & 63, wv = tid >> 6;
  const int l15 = lane & 15, koff = (lane >> 4) * 8;
  const int irow = wv * 16;
  const int ti0  = (tid & 15) * 4;
  const int tkd0 = (tid >> 4) * 4;

  bf16x8 qf[8];
#pragma unroll
  for (int ks = 0; ks < 8; ks++)
    qf[ks] = ldfrag(qb + (size_t)(row0 + irow + l15) * QS + h * 256 + ks * 32 + koff);
  float4 gq[4], cq[4];
#pragma unroll
  for (int cc = 0; cc < 4; cc++){
    gq[cc] = *reinterpret_cast<const float4*>(
        &gbuf[(size_t)(row0 + ti0 + cc) * 256 + h * 64 + tkd0]);
    cq[cc] = *reinterpret_cast<const float4*>(
        &cumbuf[(size_t)bc * 4096 + (ti0 + cc) * 64 + tkd0]);
  }
  float cumv[4][4];
#pragma unroll
  for (int nt = 0; nt < 4; nt++)
#pragma unroll
    for (int r = 0; r < 4; r++)
      cumv[nt][r] = cumbuf[(size_t)bc * 4096 +
                           (irow + (lane >> 4) * 4 + r) * 64 + nt * 16 + l15];

  f32x4 lac[4];
  {
    f32x4 qk[4];
#pragma unroll
    for (int n = 0; n < 4; n++){ qk[n] = f32x4{0.f, 0.f, 0.f, 0.f}; lac[n] = f32x4{0.f, 0.f, 0.f, 0.f}; }
#pragma unroll
    for (int ks = 0; ks < 8; ks++){
#pragma unroll
      for (int nt = 0; nt < 4; nt++){
        bf16x8 bb = ldfrag(kb + (size_t)(row0 + nt * 16 + l15) * QS + h * 256 + ks * 32 + koff);
        qk[nt] = mfma16(qf[ks], bb, qk[nt]);
      }
#pragma unroll
      for (int nt = 0; nt < 4; nt++){
        bf16x8 bh0 = ldfrag(hk0T + ((size_t)bc * 64 + nt * 16 + l15) * 256 + ks * 32 + koff);
        lac[nt] = mfma16(qf[ks], bh0, lac[nt]);
      }
    }
#pragma unroll
    for (int nt = 0; nt < 4; nt++)
#pragma unroll
      for (int r = 0; r < 4; r++){
        int i = irow + (lane >> 4) * 4 + r;
        int j = nt * 16 + l15;
        QKm[i * 72 + j] = f2bf((j <= i) ? qk[nt][r] : 0.f);
      }
  }

  u16 shv[4][4];
#pragma unroll
  for (int cc = 0; cc < 4; cc++){
#pragma unroll
    for (int d = 0; d < 4; d++){
      float pre = (1.f - __expf(f4get(gq[cc], d))) * __expf(-f4get(cq[cc], d));
      shv[cc][d] = f2bf(pre);
    }
    ushort4 w; w.x = shv[cc][0]; w.y = shv[cc][1]; w.z = shv[cc][2]; w.w = shv[cc][3];
    *reinterpret_cast<ushort4*>(&Sh[(ti0 + cc) * 72 + tkd0]) = w;
  }
#pragma unroll
  for (int d = 0; d < 4; d++){
    ushort4 w; w.x = shv[0][d]; w.y = shv[1][d]; w.z = shv[2][d]; w.w = shv[3][d];
    *reinterpret_cast<ushort4*>(&ShT[(tkd0 + d) * 72 + ti0]) = w;
  }
  float ai[4][4];
#pragma unroll
  for (int nt = 0; nt < 4; nt++)
#pragma unroll
    for (int r = 0; r < 4; r++)
      ai[nt][r] = __expf(cumv[nt][r]);

  __syncthreads();

  {
#pragma unroll
    for (int ks = 0; ks < 2; ks++){
      bf16x8 a = ldfrag(&QKm[(irow + l15) * 72 + ks * 32 + koff]);
#pragma unroll
      for (int nt = 0; nt < 4; nt++){
        bf16x8 bb = ldfrag(&ShT[(nt * 16 + l15) * 72 + ks * 32 + koff]);
        lac[nt] = mfma16(a, bb, lac[nt]);
      }
    }
#pragma unroll
    for (int r = 0; r < 4; r++){
      int i = irow + (lane >> 4) * 4 + r;
      float Lv[4];
      float mx = -3.4e38f;
#pragma unroll
      for (int nt = 0; nt < 4; nt++){
        Lv[nt] = ai[nt][r] * 0.0625f * lac[nt][r];
        mx = fmaxf(mx, Lv[nt]);
      }
#pragma unroll
      for (int d = 1; d < 16; d <<= 1) mx = fmaxf(mx, __shfl_xor(mx, d, 16));
      float sum = 0.f;
#pragma unroll
      for (int nt = 0; nt < 4; nt++){ Lv[nt] = __expf(Lv[nt] - mx); sum += Lv[nt]; }
#pragma unroll
      for (int d = 1; d < 16; d <<= 1) sum += __shfl_xor(sum, d, 16);
      float inv = 1.f / sum;
#pragma unroll
      for (int nt = 0; nt < 4; nt++)
        Pt[i * 72 + nt * 16 + l15] = f2bf(Lv[nt] * inv * ai[nt][r]);
    }
  }

  {
    f32x4 wac[4];
#pragma unroll
    for (int n = 0; n < 4; n++) wac[n] = f32x4{0.f, 0.f, 0.f, 0.f};
#pragma unroll
    for (int ks = 0; ks < 2; ks++){
      bf16x8 a = ldfrag(&Pt[(irow + l15) * 72 + ks * 32 + koff]);
#pragma unroll
      for (int nt = 0; nt < 4; nt++){
        bf16x8 bb = ldfrag(&Sh[(nt * 16 + l15) * 72 + ks * 32 + koff]);
        wac[nt] = mfma16(a, bb, wac[nt]);
      }
    }
#pragma unroll
    for (int nt = 0; nt < 4; nt++)
#pragma unroll
      for (int r = 0; r < 4; r++){
        int i = irow + (lane >> 4) * 4 + r;
        int j = nt * 16 + l15;
        QKm[i * 72 + j] = f2bf((j <= i) ? wac[nt][r] : 0.f);
      }
  }

  {
    f32x4 oac[16];
#pragma unroll
    for (int n = 0; n < 16; n++) oac[n] = f32x4{0.f, 0.f, 0.f, 0.f};
#pragma unroll
    for (int ks = 0; ks < 2; ks++){
      bf16x8 a = ldfrag(&Pt[(irow + l15) * 72 + ks * 32 + koff]);
#pragma unroll
      for (int nt = 0; nt < 16; nt++){
        bf16x8 bb = ldfrag(hv0T + ((size_t)bc * 256 + nt * 16 + l15) * 64 + ks * 32 + koff);
        oac[nt] = mfma16(a, bb, oac[nt]);
      }
    }
#pragma unroll
    for (int ks = 0; ks < 2; ks++){
      bf16x8 a = ldfrag(&QKm[(irow + l15) * 72 + ks * 32 + koff]);
#pragma unroll
      for (int nt = 0; nt < 16; nt++){
        int vd = nt * 16 + l15;
        bf16x8 bb = ldfrag(vb + (size_t)(row0 + (vd >> 2)) * QS + h * 256
                              + (vd & 3) * 64 + ks * 32 + koff);
        oac[nt] = mfma16(a, bb, oac[nt]);
      }
    }
    float gn[16];
#pragma unroll
    for (int nt = 0; nt < 16; nt++) gn[nt] = gnw[nt * 16 + l15];
#pragma unroll
    for (int r = 0; r < 4; r++){
      float ss = 0.f;
#pragma unroll
      for (int nt = 0; nt < 16; nt++) ss += oac[nt][r] * oac[nt][r];
#pragma unroll
      for (int d = 1; d < 16; d <<= 1) ss += __shfl_xor(ss, d, 16);
      float rin = rsqrtf(ss * (1.f / 256.f) + 1e-5f);
      int i = irow + (lane >> 4) * 4 + r;
#pragma unroll
      for (int nt = 0; nt < 16; nt++)
        omid[(size_t)(row0 + i) * 1024 + h * 256 + nt * 16 + l15] = f2bf(oac[nt][r] * rin * gn[nt]);
    }
  }
}

// ---------------------------------------------------------------- launch
extern "C" void kernel_launch(void* const* d_in, const int* in_sizes, int n_in,
                              void* d_out, int out_size, void* d_ws, size_t ws_size,
                              hipStream_t stream)
{
  const float* x   = (const float*)d_in[0];
  const float* Wq  = (const float*)d_in[1];
  const float* Wk  = (const float*)d_in[2];
  const float* Wv  = (const float*)d_in[3];
  const float* Wf  = (const float*)d_in[4];
  const float* gnw = (const float*)d_in[5];
  const float* Wo  = (const float*)d_in[6];
  float* out = (float*)d_out;

  char* w = (char*)d_ws;
  size_t off = 0;
  auto alloc = [&](size_t bytes)->char*{
    char* p = w + off; off += (bytes + 255) & ~(size_t)255; return p;
  };
  u16*  xb     = (u16*)alloc(8192ULL * 1024 * 2);   // later reused as o_mid
  u16*  wqkvT  = (u16*)alloc(3072ULL * 1024 * 2);   // [WqT;WkT;WvT]
  u16*  woT    = (u16*)alloc(1024ULL * 1024 * 2);
  u16*  wfT    = (u16*)alloc(256ULL  * 1024 * 2);
  u16*  qkv    = (u16*)alloc(8192ULL * 3072 * 2);   // fused q|k|v, stride 3072
  float* gbuf  = (float*)alloc(8192ULL * 256 * 4);
  u16*  UkT    = (u16*)alloc(512ULL * 64 * 256 * 2);  // becomes hk0 snapshots
  u16*  UvT    = (u16*)alloc(512ULL * 256 * 64 * 2);  // becomes hv0 snapshots
  float* alast = (float*)alloc(512ULL * 64 * 4);
  float* cumbuf= (float*)alloc(512ULL * 4096 * 4);
  if (ws_size < off) return;

  dim3 tb(32, 8);
  // merged prep: z<5 transposes, z>=5 x->bf16 convert
  k_prep<<<dim3(32, 32, 13), tb, 0, stream>>>(
      x, xb, Wq, Wk, Wv, Wo, Wf,
      wqkvT, wqkvT + 1024ULL*1024, wqkvT + 2048ULL*1024, woT, wfT);

  // gate first (small, drains under prep tail), then fused q|k|v projection
  k_gemm<2, 64><<<dim3(128, 2), 256, 0, stream>>>(xb, wfT, 1024, 256, gbuf);
  k_gemm<4, 128><<<dim3(64, 24), 256, 0, stream>>>(xb, wqkvT, 1024, 3072, qkv);

  k_pass_a<<<512, 256, 0, stream>>>(qkv + 1024, qkv + 2048, gbuf, UkT, UvT, alast, cumbuf);
  k_pass_b<<<512, 256, 0, stream>>>(UkT, UvT, alast);
  k_pass_c<<<512, 256, 0, stream>>>(qkv, qkv + 1024, qkv + 2048, gbuf, cumbuf,
                                    UkT, UvT, gnw, xb);

  k_gemm<3, 64><<<dim3(128, 8), 256, 0, stream>>>(xb, woT, 1024, 1024, out);
}

// Round 14
// 221.479 us; speedup vs baseline: 1.2034x; 1.0136x over previous
//
#include <hip/hip_runtime.h>
#include <hip/hip_bf16.h>
#include <stdint.h>

typedef unsigned short u16;
typedef __attribute__((ext_vector_type(8))) __bf16 bf16x8;
typedef __attribute__((ext_vector_type(4))) float f32x4;

#define QS 3072   // row stride of fused qkv buffer

#define DEV static __device__ __forceinline__

DEV u16 f2bf(float f){
  __hip_bfloat16 h = __float2bfloat16(f);
  return *reinterpret_cast<u16*>(&h);
}
DEV float bf2f(u16 u){
  __hip_bfloat16 h;
  *reinterpret_cast<u16*>(&h) = u;
  return __bfloat162float(h);
}
DEV f32x4 mfma16(bf16x8 a, bf16x8 b, f32x4 c){
  return __builtin_amdgcn_mfma_f32_16x16x32_bf16(a, b, c, 0, 0, 0);
}
DEV bf16x8 ldfrag(const u16* p){ return *reinterpret_cast<const bf16x8*>(p); }
DEV u16 u4get(ushort4 v, int d){ return d==0?v.x: d==1?v.y: d==2?v.z: v.w; }
DEV float f4get(float4 v, int d){ return d==0?v.x: d==1?v.y: d==2?v.z: v.w; }

DEV void gl_lds16(const u16* g, u16* l){
  __builtin_amdgcn_global_load_lds(
      (const __attribute__((address_space(1))) void*)g,
      (__attribute__((address_space(3))) void*)l, 16, 0, 0);
}

// counted-vmcnt barrier (T4): keep next tile's loads in flight across barrier
template<int N> DEV void wait_barrier(){
  if constexpr (N == 0)      asm volatile("s_waitcnt vmcnt(0)\ns_barrier" ::: "memory");
  else if constexpr (N == 3) asm volatile("s_waitcnt vmcnt(3)\ns_barrier" ::: "memory");
  else                       asm volatile("s_waitcnt vmcnt(4)\ns_barrier" ::: "memory");
}

// ---------------------------------------------------------------- prep
// Merged: z<5 -> weight transposes (Wq/Wk/Wv/Wo [1024x1024], Wf [1024x256]);
// z>=5 -> x fp32->bf16 convert (8192 logical blocks).
__global__ void k_prep(const float* __restrict__ x, u16* __restrict__ xb,
                       const float* __restrict__ s0, const float* __restrict__ s1,
                       const float* __restrict__ s2, const float* __restrict__ s3,
                       const float* __restrict__ s4,
                       u16* __restrict__ d0, u16* __restrict__ d1,
                       u16* __restrict__ d2, u16* __restrict__ d3,
                       u16* __restrict__ d4){
  const int z = blockIdx.z;
  if (z >= 5){
    int lb  = (z - 5) * 1024 + blockIdx.y * 32 + blockIdx.x;
    int tid = threadIdx.y * 32 + threadIdx.x;
    size_t i = ((size_t)lb * 256 + tid) * 4;
    float4 v = *reinterpret_cast<const float4*>(x + i);
    ushort4 o;
    o.x = f2bf(v.x); o.y = f2bf(v.y); o.z = f2bf(v.z); o.w = f2bf(v.w);
    *reinterpret_cast<ushort4*>(xb + i) = o;
    return;
  }
  const float* src = (z==0)?s0:(z==1)?s1:(z==2)?s2:(z==3)?s3:s4;
  u16* dst = (z==0)?d0:(z==1)?d1:(z==2)?d2:(z==3)?d3:d4;
  const int C = (z==4) ? 256 : 1024;
  int bx = blockIdx.x * 32, by = blockIdx.y * 32;
  if (bx >= C) return;
  __shared__ u16 t[32][33];
  int tx = threadIdx.x;
  for (int dy = threadIdx.y; dy < 32; dy += 8)
    t[dy][tx] = f2bf(src[(size_t)(by + dy) * C + bx + tx]);
  __syncthreads();
  for (int dy = threadIdx.y; dy < 32; dy += 8)
    dst[(size_t)(bx + dy) * 1024 + by + tx] = t[tx][dy];
}

// ---------------------------------------------------------------- GEMM
// BMx128 tile, 4 waves, 3-deep LDS pipeline with counted vmcnt.
// Round-8/11 proven order: barrier -> ds_read+MFMA -> stage(t+2).
// T2: st_16x32 XOR swizzle both-sides (pre-swizzled global src + swizzled
// ds_read col; LDS dest linear for global_load_lds). Conflicts measured 0.
// XCD brow-chunk swizzle: per-XCD A chunk = 2MB, L2-resident (FETCH 152->41MB).
// EPI: 2=gate f fp32, 3=fp32, 4=qkv (cols<2048 swish; bf16, single dest --
//      multi-destination mixed-dtype epilogues trigger HBM write amplification)
template<int EPI, int BM>
__global__ __launch_bounds__(256) void k_gemm(
    const u16* __restrict__ A, const u16* __restrict__ BT,
    int K, int N, void* __restrict__ out0)
{
  __shared__ u16 As[3][BM * 32];
  __shared__ u16 Bs[3][128 * 32];
  const int tid  = threadIdx.x;
  const int lane = tid & 63;
  const int wv   = tid >> 6;
  // per-XCD brow-chunk swizzle (requires gridDim.x % 8 == 0)
  const int gx  = gridDim.x;
  const int npx = gx >> 3;
  const int lin = blockIdx.y * gx + blockIdx.x;
  const int xcd = lin & 7;
  const int idx = lin >> 3;
  const int brow = (xcd * npx + (idx % npx)) * BM;
  const int bcol = (idx / npx) * 128;
  const int wr   = (wv >> 1) * (BM / 2);
  const int wc   = (wv & 1) * 64;
  const int l15  = lane & 15;
  const int koff = (lane >> 4) * 8;
  const int lr   = lane >> 2;
  const int lc8  = (lane & 3) * 8;
  const int lc8s = lc8 ^ (((lr >> 3) & 1) << 4);
  const int ksw  = koff ^ (((l15 >> 3) & 1) << 4);
  constexpr int MI = BM / 32;
  constexpr int LPS = (BM == 128) ? 4 : 3;

  f32x4 acc[MI][4];
#pragma unroll
  for (int i = 0; i < MI; i++)
#pragma unroll
    for (int j = 0; j < 4; j++) acc[i][j] = f32x4{0.f, 0.f, 0.f, 0.f};

  auto stage = [&](int buf, int kt){
    if constexpr (BM == 128){
#pragma unroll
      for (int j = 0; j < 2; j++){
        int rb = wv * 32 + j * 16;
        gl_lds16(A  + (size_t)(brow + rb + lr) * K + kt + lc8s, &As[buf][rb * 32]);
        gl_lds16(BT + (size_t)(bcol + rb + lr) * K + kt + lc8s, &Bs[buf][rb * 32]);
      }
    } else {
      gl_lds16(A + (size_t)(brow + wv * 16 + lr) * K + kt + lc8s, &As[buf][wv * 16 * 32]);
#pragma unroll
      for (int j = 0; j < 2; j++){
        int rb = wv * 32 + j * 16;
        gl_lds16(BT + (size_t)(bcol + rb + lr) * K + kt + lc8s, &Bs[buf][rb * 32]);
      }
    }
  };

  const int nit = K >> 5;
  stage(0, 0);
  stage(1, 32);
  for (int it = 0; it < nit; it++){
    const int cur = it % 3;
    if (it + 1 < nit) wait_barrier<LPS>();
    else              wait_barrier<0>();
    bf16x8 af[MI], bfv[4];
#pragma unroll
    for (int i = 0; i < MI; i++) af[i]  = ldfrag(&As[cur][(wr + i * 16 + l15) * 32 + ksw]);
#pragma unroll
    for (int j = 0; j < 4; j++) bfv[j] = ldfrag(&Bs[cur][(wc + j * 16 + l15) * 32 + ksw]);
#pragma unroll
    for (int i = 0; i < MI; i++)
#pragma unroll
      for (int j = 0; j < 4; j++)
        acc[i][j] = mfma16(af[i], bfv[j], acc[i][j]);
    if (it + 2 < nit) stage((it + 2) % 3, (it + 2) << 5);
  }

#pragma unroll
  for (int i = 0; i < MI; i++){
#pragma unroll
    for (int j = 0; j < 4; j++){
#pragma unroll
      for (int r = 0; r < 4; r++){
        int orow = brow + wr + i * 16 + (lane >> 4) * 4 + r;
        int ocol = bcol + wc + j * 16 + l15;
        size_t oi = (size_t)orow * N + ocol;
        float v = acc[i][j][r];
        if constexpr (EPI == 2){
          float ls = (v >= 0.f) ? -log1pf(__expf(-v)) : (v - log1pf(__expf(v)));
          ((float*)out0)[oi] = ls * 0.125f;          // f = log_sigmoid/8
        } else if constexpr (EPI == 3){
          ((float*)out0)[oi] = v;
        } else {                                      // EPI == 4: fused qkv
          float o = (bcol < 2048) ? v / (1.f + __expf(-v)) : v;
          ((u16*)out0)[oi] = f2bf(o);
        }
      }
    }
  }
}

// ---------------------------------------------------------------- pass A
// Register-resident cumsum; writes cumbuf f32; K^T/V^T staged via 4x4
// register transpose; V^T also written back into the consumed v-region of qkv.
__global__ __launch_bounds__(256, 3) void k_pass_a(
    const u16* __restrict__ kb, u16* __restrict__ vb,
    const float* __restrict__ gbuf,
    u16* __restrict__ UkT, u16* __restrict__ UvT, float* __restrict__ Alast,
    float* __restrict__ cumbuf)
{
  __shared__ u16 ShT[64 * 72];
  __shared__ u16 KV[256 * 72];
  __shared__ float qsum[256];
  const int bc = blockIdx.x;
  const int bh = bc >> 5, c = bc & 31;
  const int b = bh >> 2, h = bh & 3;
  const int row0 = b * 2048 + c * 64;
  const int tid = threadIdx.x;
  const int lane = tid & 63, wv = tid >> 6;
  const int l15 = lane & 15, koff = (lane >> 4) * 8;
  const int qseg = tid >> 6, m = tid & 63;
  const int ti0  = (tid & 15) * 4;
  const int tkd0 = (tid >> 4) * 4;

  ushort4 kpre[16];
#pragma unroll
  for (int it = 0; it < 4; it++)
#pragma unroll
    for (int cc = 0; cc < 4; cc++)
      kpre[it*4+cc] = *reinterpret_cast<const ushort4*>(
          kb + (size_t)(row0 + ti0 + cc) * QS + h * 256 + tkd0 + it * 64);

  float gr[16];
#pragma unroll
  for (int j = 0; j < 16; j++)
    gr[j] = gbuf[(size_t)(row0 + qseg * 16 + j) * 256 + h * 64 + m];
  float part = 0.f;
#pragma unroll
  for (int j = 0; j < 16; j++) part += gr[j];
  qsum[qseg * 64 + m] = part;
  __syncthreads();
  float run = 0.f, tot = 0.f;
#pragma unroll
  for (int jj = 0; jj < 4; jj++){
    float v = qsum[jj * 64 + m];
    tot += v;
    if (jj < qseg) run += v;
  }
  float ec63 = __expf(tot);
  if (qseg == 0) Alast[(size_t)bc * 64 + m] = ec63;
#pragma unroll
  for (int j = 0; j < 16; j++){
    run += gr[j];
    int i = qseg * 16 + j;
    float en = __expf(-run);
    float sv = 1.f - __expf(gr[j]);       // s = 1 - exp(f)
    float pre = sv * en;                   // prefix S~
    cumbuf[(size_t)bc * 4096 + i * 64 + m] = run;
    ShT[m * 72 + i] = f2bf(pre * ec63);    // suffix form for U GEMMs
  }

#pragma unroll
  for (int it = 0; it < 4; it++){
    int kd0 = tkd0 + it * 64;
#pragma unroll
    for (int d = 0; d < 4; d++){
      ushort4 w;
      w.x = u4get(kpre[it*4+0], d); w.y = u4get(kpre[it*4+1], d);
      w.z = u4get(kpre[it*4+2], d); w.w = u4get(kpre[it*4+3], d);
      *reinterpret_cast<ushort4*>(&KV[(size_t)(kd0 + d) * 72 + ti0]) = w;
    }
  }
  ushort4 vpre[16];
#pragma unroll
  for (int it = 0; it < 4; it++)
#pragma unroll
    for (int cc = 0; cc < 4; cc++)
      vpre[it*4+cc] = *reinterpret_cast<const ushort4*>(
          vb + (size_t)(row0 + ti0 + cc) * QS + h * 256 + tkd0 + it * 64);
  __syncthreads();   // drains vpre loads block-wide

  { // U_kT
    f32x4 acc[16];
#pragma unroll
    for (int n = 0; n < 16; n++) acc[n] = f32x4{0.f, 0.f, 0.f, 0.f};
#pragma unroll
    for (int ks = 0; ks < 2; ks++){
      bf16x8 a = ldfrag(&ShT[(wv * 16 + l15) * 72 + ks * 32 + koff]);
#pragma unroll
      for (int n = 0; n < 16; n++){
        bf16x8 bb = ldfrag(&KV[(n * 16 + l15) * 72 + ks * 32 + koff]);
        acc[n] = mfma16(a, bb, acc[n]);
      }
    }
#pragma unroll
    for (int n = 0; n < 16; n++)
#pragma unroll
      for (int r = 0; r < 4; r++){
        int mm = wv * 16 + (lane >> 4) * 4 + r;
        UkT[((size_t)bc * 64 + mm) * 256 + n * 16 + l15] = f2bf(acc[n][r]);
      }
  }
  __syncthreads();

  // V^T from registers -> LDS (for U_vT) AND back into the v-region of qkv
#pragma unroll
  for (int it = 0; it < 4; it++){
    int kd0 = tkd0 + it * 64;
#pragma unroll
    for (int d = 0; d < 4; d++){
      int vd = kd0 + d;
      ushort4 w;
      w.x = u4get(vpre[it*4+0], d); w.y = u4get(vpre[it*4+1], d);
      w.z = u4get(vpre[it*4+2], d); w.w = u4get(vpre[it*4+3], d);
      *reinterpret_cast<ushort4*>(&KV[(size_t)vd * 72 + ti0]) = w;
      *reinterpret_cast<ushort4*>(
          vb + (size_t)(row0 + (vd >> 2)) * QS + h * 256 + (vd & 3) * 64 + ti0) = w;
    }
  }
  __syncthreads();

  { // U_vT
    f32x4 acc[4][4];
#pragma unroll
    for (int i = 0; i < 4; i++)
#pragma unroll
      for (int j = 0; j < 4; j++) acc[i][j] = f32x4{0.f, 0.f, 0.f, 0.f};
#pragma unroll
    for (int ks = 0; ks < 2; ks++){
      bf16x8 a[4], bb[4];
#pragma unroll
      for (int mt = 0; mt < 4; mt++)
        a[mt] = ldfrag(&KV[(wv * 64 + mt * 16 + l15) * 72 + ks * 32 + koff]);
#pragma unroll
      for (int nt = 0; nt < 4; nt++)
        bb[nt] = ldfrag(&ShT[(nt * 16 + l15) * 72 + ks * 32 + koff]);
#pragma unroll
      for (int mt = 0; mt < 4; mt++)
#pragma unroll
        for (int nt = 0; nt < 4; nt++)
          acc[mt][nt] = mfma16(a[mt], bb[nt], acc[mt][nt]);
    }
#pragma unroll
    for (int mt = 0; mt < 4; mt++)
#pragma unroll
      for (int nt = 0; nt < 4; nt++)
#pragma unroll
        for (int r = 0; r < 4; r++){
          int vd = wv * 64 + mt * 16 + (lane >> 4) * 4 + r;
          UvT[((size_t)bc * 256 + vd) * 64 + nt * 16 + l15] = f2bf(acc[mt][nt][r]);
        }
  }
}

// ---------------------------------------------------------------- pass B
__global__ __launch_bounds__(256) void k_pass_b(
    u16* __restrict__ UkT, u16* __restrict__ UvT, const float* __restrict__ Alast)
{
  const int blk  = blockIdx.x;
  const int bh   = blk >> 5;
  const int slab = blk & 31;
  const int tid  = threadIdx.x;
  const bool isV = slab >= 16;
  u16* U = isV ? UvT : UkT;
  const int e0 = (slab & 15) * 1024 + tid * 4;
  const size_t base = (size_t)bh * 32 * 16384 + e0;
  const float* alb = Alast + (size_t)bh * 32 * 64;
  const int mK = e0 >> 8;
  const int mV = e0 & 63;

  float h0 = 0.f, h1 = 0.f, h2 = 0.f, h3 = 0.f;
  ushort4 u0 = *reinterpret_cast<ushort4*>(&U[base]);
  ushort4 u1 = *reinterpret_cast<ushort4*>(&U[base + 16384]);
  for (int c = 0; c < 32; c++){
    const int cn = (c + 2 < 32) ? c + 2 : 31;
    ushort4 u2 = *reinterpret_cast<ushort4*>(&U[base + (size_t)cn * 16384]);
    float a0, a1, a2, a3;
    if (isV){
      float4 av = *reinterpret_cast<const float4*>(alb + c * 64 + mV);
      a0 = av.x; a1 = av.y; a2 = av.z; a3 = av.w;
    } else {
      float av = alb[c * 64 + mK];
      a0 = a1 = a2 = a3 = av;
    }
    ushort4 s;
    s.x = f2bf(h0); s.y = f2bf(h1); s.z = f2bf(h2); s.w = f2bf(h3);
    *reinterpret_cast<ushort4*>(&U[base + (size_t)c * 16384]) = s;
    h0 = h0 * a0 + bf2f(u0.x);
    h1 = h1 * a1 + bf2f(u0.y);
    h2 = h2 * a2 + bf2f(u0.z);
    h3 = h3 * a3 + bf2f(u0.w);
    u0 = u1; u1 = u2;
  }
}

// ---------------------------------------------------------------- pass C
// LDS 36.9KB -> 4 blocks/CU (VT read straight from the transposed v-region).
__global__ __launch_bounds__(256, 4) void k_pass_c(
    const u16* __restrict__ qb, const u16* __restrict__ kb, const u16* __restrict__ vb,
    const float* __restrict__ gbuf, const float* __restrict__ cumbuf,
    const u16* __restrict__ hk0T, const u16* __restrict__ hv0T,
    const float* __restrict__ gnw, u16* __restrict__ omid)
{
  __shared__ u16 Sh [64 * 72];
  __shared__ u16 ShT[64 * 72];
  __shared__ u16 QKm[64 * 72];
  __shared__ u16 Pt [64 * 72];
  const int bc = blockIdx.x;
  const int bh = bc >> 5, c = bc & 31;
  const int b = bh >> 2, h = bh & 3;
  const int row0 = b * 2048 + c * 64;
  const int tid = threadIdx.x, lane = tid & 63, wv = tid >> 6;
  const int l15 = lane & 15, koff = (lane >> 4) * 8;
  const int irow = wv * 16;
  const int ti0  = (tid & 15) * 4;
  const int tkd0 = (tid >> 4) * 4;

  // ---- prefetches (overlap phase-1 compute)
  bf16x8 qf[8];
#pragma unroll
  for (int ks = 0; ks < 8; ks++)
    qf[ks] = ldfrag(qb + (size_t)(row0 + irow + l15) * QS + h * 256 + ks * 32 + koff);
  float4 gq[4], cq[4];
#pragma unroll
  for (int cc = 0; cc < 4; cc++){
    gq[cc] = *reinterpret_cast<const float4*>(
        &gbuf[(size_t)(row0 + ti0 + cc) * 256 + h * 64 + tkd0]);
    cq[cc] = *reinterpret_cast<const float4*>(
        &cumbuf[(size_t)bc * 4096 + (ti0 + cc) * 64 + tkd0]);
  }
  float cumv[4][4];
#pragma unroll
  for (int nt = 0; nt < 4; nt++)
#pragma unroll
    for (int r = 0; r < 4; r++)
      cumv[nt][r] = cumbuf[(size_t)bc * 4096 +
                           (irow + (lane >> 4) * 4 + r) * 64 + nt * 16 + l15];

  // ---- phase 1: qk = Q.K^T, lac = Q.hk0^T
  f32x4 lac[4];
  {
    f32x4 qk[4];
#pragma unroll
    for (int n = 0; n < 4; n++){ qk[n] = f32x4{0.f, 0.f, 0.f, 0.f}; lac[n] = f32x4{0.f, 0.f, 0.f, 0.f}; }
#pragma unroll
    for (int ks = 0; ks < 8; ks++){
#pragma unroll
      for (int nt = 0; nt < 4; nt++){
        bf16x8 bb = ldfrag(kb + (size_t)(row0 + nt * 16 + l15) * QS + h * 256 + ks * 32 + koff);
        qk[nt] = mfma16(qf[ks], bb, qk[nt]);
      }
#pragma unroll
      for (int nt = 0; nt < 4; nt++){
        bf16x8 bh0 = ldfrag(hk0T + ((size_t)bc * 64 + nt * 16 + l15) * 256 + ks * 32 + koff);
        lac[nt] = mfma16(qf[ks], bh0, lac[nt]);
      }
    }
#pragma unroll
    for (int nt = 0; nt < 4; nt++)
#pragma unroll
      for (int r = 0; r < 4; r++){
        int i = irow + (lane >> 4) * 4 + r;
        int j = nt * 16 + l15;
        QKm[i * 72 + j] = f2bf((j <= i) ? qk[nt][r] : 0.f);
      }
  }

  // ---- stage Sh/ShT (from g + cum)
  u16 shv[4][4];
#pragma unroll
  for (int cc = 0; cc < 4; cc++){
#pragma unroll
    for (int d = 0; d < 4; d++){
      float pre = (1.f - __expf(f4get(gq[cc], d))) * __expf(-f4get(cq[cc], d));
      shv[cc][d] = f2bf(pre);
    }
    ushort4 w; w.x = shv[cc][0]; w.y = shv[cc][1]; w.z = shv[cc][2]; w.w = shv[cc][3];
    *reinterpret_cast<ushort4*>(&Sh[(ti0 + cc) * 72 + tkd0]) = w;
  }
#pragma unroll
  for (int d = 0; d < 4; d++){
    ushort4 w; w.x = shv[0][d]; w.y = shv[1][d]; w.z = shv[2][d]; w.w = shv[3][d];
    *reinterpret_cast<ushort4*>(&ShT[(tkd0 + d) * 72 + ti0]) = w;
  }
  float ai[4][4];
#pragma unroll
  for (int nt = 0; nt < 4; nt++)
#pragma unroll
    for (int r = 0; r < 4; r++)
      ai[nt][r] = __expf(cumv[nt][r]);

  __syncthreads();   // the only barrier: Sh/ShT ready for all waves

  // ---- phase 2b: lac += QKm.ShT ; softmax ; Pt = p*ai
  {
#pragma unroll
    for (int ks = 0; ks < 2; ks++){
      bf16x8 a = ldfrag(&QKm[(irow + l15) * 72 + ks * 32 + koff]);
#pragma unroll
      for (int nt = 0; nt < 4; nt++){
        bf16x8 bb = ldfrag(&ShT[(nt * 16 + l15) * 72 + ks * 32 + koff]);
        lac[nt] = mfma16(a, bb, lac[nt]);
      }
    }
#pragma unroll
    for (int r = 0; r < 4; r++){
      int i = irow + (lane >> 4) * 4 + r;
      float Lv[4];
      float mx = -3.4e38f;
#pragma unroll
      for (int nt = 0; nt < 4; nt++){
        Lv[nt] = ai[nt][r] * 0.0625f * lac[nt][r];
        mx = fmaxf(mx, Lv[nt]);
      }
#pragma unroll
      for (int d = 1; d < 16; d <<= 1) mx = fmaxf(mx, __shfl_xor(mx, d, 16));
      float sum = 0.f;
#pragma unroll
      for (int nt = 0; nt < 4; nt++){ Lv[nt] = __expf(Lv[nt] - mx); sum += Lv[nt]; }
#pragma unroll
      for (int d = 1; d < 16; d <<= 1) sum += __shfl_xor(sum, d, 16);
      float inv = 1.f / sum;
#pragma unroll
      for (int nt = 0; nt < 4; nt++)
        Pt[i * 72 + nt * 16 + l15] = f2bf(Lv[nt] * inv * ai[nt][r]);
    }
  }

  // ---- phase 3: W = tril(Pt Sh^T) -> QKm (wave-private rows)
  {
    f32x4 wac[4];
#pragma unroll
    for (int n = 0; n < 4; n++) wac[n] = f32x4{0.f, 0.f, 0.f, 0.f};
#pragma unroll
    for (int ks = 0; ks < 2; ks++){
      bf16x8 a = ldfrag(&Pt[(irow + l15) * 72 + ks * 32 + koff]);
#pragma unroll
      for (int nt = 0; nt < 4; nt++){
        bf16x8 bb = ldfrag(&Sh[(nt * 16 + l15) * 72 + ks * 32 + koff]);
        wac[nt] = mfma16(a, bb, wac[nt]);
      }
    }
#pragma unroll
    for (int nt = 0; nt < 4; nt++)
#pragma unroll
      for (int r = 0; r < 4; r++){
        int i = irow + (lane >> 4) * 4 + r;
        int j = nt * 16 + l15;
        QKm[i * 72 + j] = f2bf((j <= i) ? wac[nt][r] : 0.f);
      }
  }

  // ---- phase 4: O = Pt hv0 + W V ; fused RMSNorm
  {
    f32x4 oac[16];
#pragma unroll
    for (int n = 0; n < 16; n++) oac[n] = f32x4{0.f, 0.f, 0.f, 0.f};
#pragma unroll
    for (int ks = 0; ks < 2; ks++){
      bf16x8 a = ldfrag(&Pt[(irow + l15) * 72 + ks * 32 + koff]);
#pragma unroll
      for (int nt = 0; nt < 16; nt++){
        bf16x8 bb = ldfrag(hv0T + ((size_t)bc * 256 + nt * 16 + l15) * 64 + ks * 32 + koff);
        oac[nt] = mfma16(a, bb, oac[nt]);
      }
    }
#pragma unroll
    for (int ks = 0; ks < 2; ks++){
      bf16x8 a = ldfrag(&QKm[(irow + l15) * 72 + ks * 32 + koff]);
#pragma unroll
      for (int nt = 0; nt < 16; nt++){
        int vd = nt * 16 + l15;
        bf16x8 bb = ldfrag(vb + (size_t)(row0 + (vd >> 2)) * QS + h * 256
                              + (vd & 3) * 64 + ks * 32 + koff);
        oac[nt] = mfma16(a, bb, oac[nt]);
      }
    }
    float gn[16];
#pragma unroll
    for (int nt = 0; nt < 16; nt++) gn[nt] = gnw[nt * 16 + l15];
#pragma unroll
    for (int r = 0; r < 4; r++){
      float ss = 0.f;
#pragma unroll
      for (int nt = 0; nt < 16; nt++) ss += oac[nt][r] * oac[nt][r];
#pragma unroll
      for (int d = 1; d < 16; d <<= 1) ss += __shfl_xor(ss, d, 16);
      float rin = rsqrtf(ss * (1.f / 256.f) + 1e-5f);
      int i = irow + (lane >> 4) * 4 + r;
#pragma unroll
      for (int nt = 0; nt < 16; nt++)
        omid[(size_t)(row0 + i) * 1024 + h * 256 + nt * 16 + l15] = f2bf(oac[nt][r] * rin * gn[nt]);
    }
  }
}

// ---------------------------------------------------------------- launch
extern "C" void kernel_launch(void* const* d_in, const int* in_sizes, int n_in,
                              void* d_out, int out_size, void* d_ws, size_t ws_size,
                              hipStream_t stream)
{
  const float* x   = (const float*)d_in[0];
  const float* Wq  = (const float*)d_in[1];
  const float* Wk  = (const float*)d_in[2];
  const float* Wv  = (const float*)d_in[3];
  const float* Wf  = (const float*)d_in[4];
  const float* gnw = (const float*)d_in[5];
  const float* Wo  = (const float*)d_in[6];
  float* out = (float*)d_out;

  char* w = (char*)d_ws;
  size_t off = 0;
  auto alloc = [&](size_t bytes)->char*{
    char* p = w + off; off += (bytes + 255) & ~(size_t)255; return p;
  };
  u16*  xb     = (u16*)alloc(8192ULL * 1024 * 2);   // later reused as o_mid
  u16*  wqkvT  = (u16*)alloc(3072ULL * 1024 * 2);   // [WqT;WkT;WvT]
  u16*  woT    = (u16*)alloc(1024ULL * 1024 * 2);
  u16*  wfT    = (u16*)alloc(256ULL  * 1024 * 2);
  u16*  qkv    = (u16*)alloc(8192ULL * 3072 * 2);   // fused q|k|v, stride 3072
  float* gbuf  = (float*)alloc(8192ULL * 256 * 4);
  u16*  UkT    = (u16*)alloc(512ULL * 64 * 256 * 2);  // becomes hk0 snapshots
  u16*  UvT    = (u16*)alloc(512ULL * 256 * 64 * 2);  // becomes hv0 snapshots
  float* alast = (float*)alloc(512ULL * 64 * 4);
  float* cumbuf= (float*)alloc(512ULL * 4096 * 4);
  if (ws_size < off) return;

  dim3 tb(32, 8);
  // merged prep: z<5 transposes, z>=5 x->bf16 convert
  k_prep<<<dim3(32, 32, 13), tb, 0, stream>>>(
      x, xb, Wq, Wk, Wv, Wo, Wf,
      wqkvT, wqkvT + 1024ULL*1024, wqkvT + 2048ULL*1024, woT, wfT);

  // fused q|k|v projection (single-destination epilogue) + separate gate GEMM
  k_gemm<4, 128><<<dim3(64, 24), 256, 0, stream>>>(xb, wqkvT, 1024, 3072, qkv);
  k_gemm<2, 64><<<dim3(128, 2), 256, 0, stream>>>(xb, wfT, 1024, 256, gbuf);

  k_pass_a<<<512, 256, 0, stream>>>(qkv + 1024, qkv + 2048, gbuf, UkT, UvT, alast, cumbuf);
  k_pass_b<<<512, 256, 0, stream>>>(UkT, UvT, alast);
  k_pass_c<<<512, 256, 0, stream>>>(qkv, qkv + 1024, qkv + 2048, gbuf, cumbuf,
                                    UkT, UvT, gnw, xb);

  k_gemm<3, 64><<<dim3(128, 8), 256, 0, stream>>>(xb, woT, 1024, 1024, out);
}